// Round 1
// baseline (373.314 us; speedup 1.0000x reference)
//
#include <hip/hip_runtime.h>
#include <hip/hip_bf16.h>
#include <hip/hip_fp16.h>

#define NN 100000
#define NE 1600000
#define NCHUNK ((NN + 127) / 128)   // 782 (gemm row chunks of 128)
#define NPB 512                      // nodes per bucket (pow2, shift 9)
#define NB 256                       // bucket slots (196 active)
#define CHUNK 8192                   // edges per bscatter block
#define NCH ((NE + CHUNK - 1) / CHUNK)  // 196

typedef __attribute__((ext_vector_type(8))) short short8;
typedef __attribute__((ext_vector_type(4))) float float4v;
typedef __attribute__((ext_vector_type(2))) float float2v;

__device__ __forceinline__ unsigned short f2bf(float f) {
    unsigned int b = __float_as_uint(f);
    return (unsigned short)((b + 0x7fffu + ((b >> 16) & 1u)) >> 16);
}
__device__ __forceinline__ unsigned int pack_bf16(float lo, float hi) {
    return (unsigned int)f2bf(lo) | ((unsigned int)f2bf(hi) << 16);
}
// 8 fp8 (e4m3) in a uint2 -> accumulate into a[0..7]
__device__ __forceinline__ void addp8(float* a, uint2 u) {
    float2v f;
    f = __builtin_amdgcn_cvt_pk_f32_fp8(u.x, false); a[0] += f.x; a[1] += f.y;
    f = __builtin_amdgcn_cvt_pk_f32_fp8(u.x, true);  a[2] += f.x; a[3] += f.y;
    f = __builtin_amdgcn_cvt_pk_f32_fp8(u.y, false); a[4] += f.x; a[5] += f.y;
    f = __builtin_amdgcn_cvt_pk_f32_fp8(u.y, true);  a[6] += f.x; a[7] += f.y;
}
__device__ __forceinline__ unsigned char f2fp8(float v) {
    int r = __builtin_amdgcn_cvt_pk_fp8_f32(v, v, 0, false);
    return (unsigned char)(r & 0xff);
}
__device__ __forceinline__ unsigned short pack2fp8(float lo, float hi) {
    int r = __builtin_amdgcn_cvt_pk_fp8_f32(lo, hi, 0, false);
    return (unsigned short)(r & 0xffff);
}
__device__ __forceinline__ float h2f(unsigned short u) {
    return __half2float(__ushort_as_half(u));
}

// ---- fused prep: xconv (blocks 0..24999), wconv (25000..25127), bcount (25128..25383) ----
__global__ void k_prep(const float* x, const float* W1l, const float* W1r,
                       const float* W2l, const float* W2r, const int* ei,
                       unsigned int* axb_u, unsigned short* xf8, unsigned short* wb1,
                       unsigned short* wb2, int* bcnt) {
    __shared__ int hh[NB];
    int b = blockIdx.x, t = threadIdx.x;
    if (b < 25000) {
        int tt = b * 256 + t;
        int node = tt >> 6, i = tt & 63;
        float2 v = ((const float2*)x)[tt];
        axb_u[(size_t)node * 128 + 64 + i] = pack_bf16(v.x, v.y);
        xf8[(size_t)node * 64 + i] = pack2fp8(v.x, v.y);
    } else if (b < 25128) {
        int i = (b - 25000) * 256 + t;        // < 32768
        int r1 = i >> 7, c1 = i & 127;        // W1l/W1r are 256x128
        wb1[r1 * 256 + c1]       = f2bf(W1l[i]);
        wb1[r1 * 256 + 128 + c1] = f2bf(W1r[i]);
        wb2[i]         = f2bf(W2l[i]);        // 128x256, k contiguous
        wb2[32768 + i] = f2bf(W2r[i]);
    } else {
        hh[t] = 0;
        __syncthreads();
        int e0 = (b - 25128) * 6250;          // 256 * 6250 = NE exactly
        for (int e = e0 + t; e < e0 + 6250; e += 256)
            atomicAdd(&hh[ei[NE + e] >> 9], 1);
        __syncthreads();
        if (hh[t]) atomicAdd(&bcnt[t], hh[t]);
    }
}

__global__ void k_bscan(const int* bcnt, int* boff, int* bcur) {
    __shared__ int s[NB];
    int t = threadIdx.x;
    int v = bcnt[t];
    s[t] = v;
    __syncthreads();
    for (int d = 1; d < NB; d <<= 1) {
        int val = (t >= d) ? s[t - d] : 0;
        __syncthreads();
        s[t] += val;
        __syncthreads();
    }
    boff[t + 1] = s[t];
    if (t == 0) boff[0] = 0;
    bcur[t] = s[t] - v;   // exclusive
}

// pairs packed: bits[0:17)=row, bits[17:26)=col&511 (bucket-local)
__global__ __launch_bounds__(256) void k_bscatter(const int* ei, int* bcur, unsigned int* pairs) {
    __shared__ unsigned int buf[CHUNK];   // 32 KB
    __shared__ int cnt[NB];
    __shared__ int lbase[NB];
    __shared__ int lcur[NB];
    __shared__ int gpos[NB];
    int t = threadIdx.x;
    int e0 = blockIdx.x * CHUNK;
    int nedge = NE - e0; if (nedge > CHUNK) nedge = CHUNK;
    cnt[t] = 0;
    __syncthreads();
    for (int i = t; i < nedge; i += 256)
        atomicAdd(&cnt[ei[NE + e0 + i] >> 9], 1);
    __syncthreads();
    int v = cnt[t];
    lcur[t] = v;
    __syncthreads();
    for (int d = 1; d < NB; d <<= 1) {
        int val = (t >= d) ? lcur[t - d] : 0;
        __syncthreads();
        lcur[t] += val;
        __syncthreads();
    }
    lbase[t] = lcur[t] - v;
    gpos[t] = atomicAdd(&bcur[t], v);
    __syncthreads();
    lcur[t] = lbase[t];
    __syncthreads();
    for (int i = t; i < nedge; i += 256) {
        int r = ei[e0 + i], c = ei[NE + e0 + i];
        int b = c >> 9;
        int p = atomicAdd(&lcur[b], 1);
        buf[p] = (unsigned)r | ((unsigned)(c & 511) << 17);
    }
    __syncthreads();
    // coalesced flush: wave wv handles buckets wv, wv+4, ...; lanes stride inside
    int wv = t >> 6, lane = t & 63;
    for (int b = wv; b < NB; b += 4) {
        int n = cnt[b], lb = lbase[b], gp = gpos[b];
        for (int i = lane; i < n; i += 64)
            pairs[gp + i] = buf[lb + i];
    }
}

__global__ __launch_bounds__(256) void k_build(const unsigned int* pairs, const int* boff,
                                               int* off, int* deg, int* csr) {
    __shared__ int ldeg[NPB];
    __shared__ int lcur[NPB];
    __shared__ int sscan[256];
    int b = blockIdx.x;
    int nbase = b * NPB;
    if (nbase >= NN) return;
    int t = threadIdx.x;
    int base = boff[b], cntb = boff[b + 1] - base;
    ldeg[t] = 0; ldeg[t + 256] = 0;
    __syncthreads();
    for (int i = t; i < cntb; i += 256) {
        unsigned int pr = pairs[base + i];
        atomicAdd(&ldeg[pr >> 17], 1);
    }
    __syncthreads();
    int d0 = ldeg[2 * t], d1 = ldeg[2 * t + 1];
    int v = d0 + d1;
    sscan[t] = v;
    __syncthreads();
    for (int d = 1; d < 256; d <<= 1) {
        int val = (t >= d) ? sscan[t - d] : 0;
        __syncthreads();
        sscan[t] += val;
        __syncthreads();
    }
    int ex = sscan[t] - v;
    lcur[2 * t] = ex; lcur[2 * t + 1] = ex + d0;
    __syncthreads();
    int nloc = NN - nbase; if (nloc > NPB) nloc = NPB;
    for (int ln = t; ln < nloc; ln += 256) {
        off[nbase + ln] = base + lcur[ln];
        deg[nbase + ln] = ldeg[ln];
    }
    __syncthreads();
    for (int i = t; i < cntb; i += 256) {
        unsigned int pr = pairs[base + i];
        int p = atomicAdd(&lcur[pr >> 17], 1);
        csr[base + p] = (int)(pr & 0x1FFFFu);
    }
}

// ---- agg1: mean of xf8 (fp8) over neighbors -> axb cols 0..127 (bf16) ----
__global__ void k_agg1(const uint2* xf8, const int* off, const int* deg,
                       const int* csr, unsigned int* axb_w) {
    int wid = (blockIdx.x * 256 + threadIdx.x) >> 6;
    if (wid >= NN) return;
    int lane = threadIdx.x & 63;
    int sub = lane >> 4, l16 = lane & 15;
    int start = off[wid], d = deg[wid];
    const uint2* gp = xf8 + l16;   // row stride = 16 uint2 (128 B)
    float a[8] = {0.f, 0.f, 0.f, 0.f, 0.f, 0.f, 0.f, 0.f};
    int j = sub;
    for (; j + 4 < d; j += 8) {
        int n0 = csr[start + j];
        int n1 = csr[start + j + 4];
        uint2 u0 = gp[(size_t)n0 * 16];
        uint2 u1 = gp[(size_t)n1 * 16];
        addp8(a, u0); addp8(a, u1);
    }
    if (j < d) {
        int nb = csr[start + j];
        uint2 u = gp[(size_t)nb * 16];
        addp8(a, u);
    }
#pragma unroll
    for (int i = 0; i < 8; i++) {
        a[i] += __shfl_xor(a[i], 16, 64);
        a[i] += __shfl_xor(a[i], 32, 64);
    }
    if (sub == 0) {
        float inv = 1.0f / (float)(d > 0 ? d : 1);
        uint4 o;
        o.x = pack_bf16(a[0] * inv, a[1] * inv);
        o.y = pack_bf16(a[2] * inv, a[3] * inv);
        o.z = pack_bf16(a[4] * inv, a[5] * inv);
        o.w = pack_bf16(a[6] * inv, a[7] * inv);
        *(uint4*)(axb_w + (size_t)wid * 128 + (l16 << 2)) = o;
    }
}

// ---- agg2: out = partial(f16) + mean of g (fp8) over neighbors ----
__global__ void k_agg2(const uint2* g, const int* off, const int* deg,
                       const int* csr, const unsigned short* partial, float* out) {
    int wid = (blockIdx.x * 256 + threadIdx.x) >> 6;
    if (wid >= NN) return;
    int lane = threadIdx.x & 63;
    int sub = lane >> 4, l16 = lane & 15;
    int start = off[wid], d = deg[wid];
    const uint2* gp = g + l16;   // row stride = 16 uint2 (128 B)
    float a[8] = {0.f, 0.f, 0.f, 0.f, 0.f, 0.f, 0.f, 0.f};
    int j = sub;
    for (; j + 4 < d; j += 8) {
        int n0 = csr[start + j];
        int n1 = csr[start + j + 4];
        uint2 u0 = gp[(size_t)n0 * 16];
        uint2 u1 = gp[(size_t)n1 * 16];
        addp8(a, u0); addp8(a, u1);
    }
    if (j < d) {
        int nb = csr[start + j];
        uint2 u = gp[(size_t)nb * 16];
        addp8(a, u);
    }
#pragma unroll
    for (int i = 0; i < 8; i++) {
        a[i] += __shfl_xor(a[i], 16, 64);
        a[i] += __shfl_xor(a[i], 32, 64);
    }
    if (sub == 0) {
        float inv = 1.0f / (float)(d > 0 ? d : 1);
        uint4 pu = *(const uint4*)(partial + (size_t)wid * 128 + (l16 << 3));
        float4 c0, c1;
        c0.x = h2f(pu.x & 0xffff) + a[0] * inv; c0.y = h2f(pu.x >> 16) + a[1] * inv;
        c0.z = h2f(pu.y & 0xffff) + a[2] * inv; c0.w = h2f(pu.y >> 16) + a[3] * inv;
        c1.x = h2f(pu.z & 0xffff) + a[4] * inv; c1.y = h2f(pu.z >> 16) + a[5] * inv;
        c1.z = h2f(pu.w & 0xffff) + a[6] * inv; c1.w = h2f(pu.w >> 16) + a[7] * inv;
        float4* po = (float4*)(out + (size_t)wid * 128) + (l16 << 1);
        po[0] = c0; po[1] = c1;
    }
}

// ---- GEMM1 (col-split): block = 128 rows x 64 cols of relu(A@wb1^T + b1) -> H (bf16) ----
// grid = NCHUNK*4; cg = blockIdx&3 owns output cols [cg*64, cg*64+64)
// B slice in LDS: 64 rows x 264 ushorts (8-ushort pad -> per-row bank-group rotation)
#define BROW 264
__global__ __launch_bounds__(256, 4) void k_gemm1(const unsigned short* A, const unsigned short* wb,
                                                  const float* b1, unsigned short* H) {
    __shared__ unsigned short Bs[64 * BROW];   // 33 KB
    int t = threadIdx.x;
    int cg = blockIdx.x & 3, chunk = blockIdx.x >> 2;
    {
        const short8* src = (const short8*)(wb + (size_t)cg * 64 * 256);
        short8* dst = (short8*)Bs;   // 33 granules per row
#pragma unroll
        for (int i = 0; i < 8; i++) {
            int gi = i * 256 + t;             // 2048 granules of 16B
            int r = gi >> 5, c = gi & 31;
            dst[r * 33 + c] = src[gi];
        }
    }
    __syncthreads();
    int wv = t >> 6, lane = t & 63;
    int mrow = lane & 15, quad = lane >> 4;
    int base = chunk * 128 + wv * 32;
    if (base >= NN) return;
    float bias[4];
#pragma unroll
    for (int ctl = 0; ctl < 4; ctl++) bias[ctl] = b1[cg * 64 + ctl * 16 + mrow];
    float4v acc[2][4];
#pragma unroll
    for (int h = 0; h < 2; h++)
#pragma unroll
        for (int ctl = 0; ctl < 4; ctl++) acc[h][ctl] = (float4v)(0.0f);
    const short8* a0p = (const short8*)(A + (size_t)(base + mrow) * 256);
    const short8* a1p = (const short8*)(A + (size_t)(base + 16 + mrow) * 256);
#pragma unroll
    for (int kk = 0; kk < 8; kk++) {
        short8 a0 = a0p[kk * 4 + quad];
        short8 a1 = a1p[kk * 4 + quad];
        int koff = kk * 32 + quad * 8;
#pragma unroll
        for (int ctl = 0; ctl < 4; ctl++) {
            short8 b = *(const short8*)(Bs + (ctl * 16 + mrow) * BROW + koff);
            acc[0][ctl] = __builtin_amdgcn_mfma_f32_16x16x32_bf16(a0, b, acc[0][ctl], 0, 0, 0);
            acc[1][ctl] = __builtin_amdgcn_mfma_f32_16x16x32_bf16(a1, b, acc[1][ctl], 0, 0, 0);
        }
    }
#pragma unroll
    for (int ctl = 0; ctl < 4; ctl++) {
        int col = cg * 64 + ctl * 16 + mrow;
#pragma unroll
        for (int h = 0; h < 2; h++)
#pragma unroll
            for (int r = 0; r < 4; r++) {
                int node = base + h * 16 + quad * 4 + r;
                float v = acc[h][ctl][r] + bias[ctl];
                H[(size_t)node * 256 + col] = f2bf(fmaxf(v, 0.f));
            }
    }
}

// ---- GEMM2 (col-split): cg 0,1 -> g (fp8, cols 0..127); cg 2,3 -> partial f16 (+b2) ----
__global__ __launch_bounds__(256, 4) void k_gemm2(const unsigned short* A, const unsigned short* wb,
                                                  const float* b2, unsigned char* g,
                                                  unsigned short* partial) {
    __shared__ unsigned short Bs[64 * BROW];   // 33 KB
    int t = threadIdx.x;
    int cg = blockIdx.x & 3, chunk = blockIdx.x >> 2;
    {
        const short8* src = (const short8*)(wb + (size_t)cg * 64 * 256);
        short8* dst = (short8*)Bs;
#pragma unroll
        for (int i = 0; i < 8; i++) {
            int gi = i * 256 + t;
            int r = gi >> 5, c = gi & 31;
            dst[r * 33 + c] = src[gi];
        }
    }
    __syncthreads();
    int wv = t >> 6, lane = t & 63;
    int mrow = lane & 15, quad = lane >> 4;
    int base = chunk * 128 + wv * 32;
    if (base >= NN) return;
    float bias[4];
#pragma unroll
    for (int ctl = 0; ctl < 4; ctl++)
        bias[ctl] = (cg >= 2) ? b2[cg * 64 + ctl * 16 + mrow - 128] : 0.f;
    float4v acc[2][4];
#pragma unroll
    for (int h = 0; h < 2; h++)
#pragma unroll
        for (int ctl = 0; ctl < 4; ctl++) acc[h][ctl] = (float4v)(0.0f);
    const short8* a0p = (const short8*)(A + (size_t)(base + mrow) * 256);
    const short8* a1p = (const short8*)(A + (size_t)(base + 16 + mrow) * 256);
#pragma unroll
    for (int kk = 0; kk < 8; kk++) {
        short8 a0 = a0p[kk * 4 + quad];
        short8 a1 = a1p[kk * 4 + quad];
        int koff = kk * 32 + quad * 8;
#pragma unroll
        for (int ctl = 0; ctl < 4; ctl++) {
            short8 b = *(const short8*)(Bs + (ctl * 16 + mrow) * BROW + koff);
            acc[0][ctl] = __builtin_amdgcn_mfma_f32_16x16x32_bf16(a0, b, acc[0][ctl], 0, 0, 0);
            acc[1][ctl] = __builtin_amdgcn_mfma_f32_16x16x32_bf16(a1, b, acc[1][ctl], 0, 0, 0);
        }
    }
    if (cg < 2) {
#pragma unroll
        for (int ctl = 0; ctl < 4; ctl++) {
            int col = cg * 64 + ctl * 16 + mrow;   // in [0,128)
#pragma unroll
            for (int h = 0; h < 2; h++)
#pragma unroll
                for (int r = 0; r < 4; r++) {
                    int node = base + h * 16 + quad * 4 + r;
                    g[(size_t)node * 128 + col] = f2fp8(acc[h][ctl][r]);
                }
        }
    } else {
#pragma unroll
        for (int ctl = 0; ctl < 4; ctl++) {
            int pcol = cg * 64 + ctl * 16 + mrow - 128;   // in [0,128)
#pragma unroll
            for (int h = 0; h < 2; h++)
#pragma unroll
                for (int r = 0; r < 4; r++) {
                    int node = base + h * 16 + quad * 4 + r;
                    __half hf = __float2half(acc[h][ctl][r] + bias[ctl]);
                    partial[(size_t)node * 128 + pcol] = __half_as_ushort(hf);
                }
        }
    }
}

extern "C" void kernel_launch(void* const* d_in, const int* in_sizes, int n_in,
                              void* d_out, int out_size, void* d_ws, size_t ws_size,
                              hipStream_t stream) {
    const float* x   = (const float*)d_in[0];
    const int*   ei  = (const int*)d_in[1];
    const float* W1l = (const float*)d_in[2];
    const float* b1  = (const float*)d_in[3];
    const float* W1r = (const float*)d_in[4];
    const float* W2l = (const float*)d_in[5];
    const float* b2  = (const float*)d_in[6];
    const float* W2r = (const float*)d_in[7];
    float* out = (float*)d_out;

    char* p = (char*)d_ws;
    unsigned int* axb = (unsigned int*)p; p += (size_t)NN * 256 * 2;  // [agg(128) | x(128)] bf16
    unsigned short* h = (unsigned short*)p; p += (size_t)NN * 256 * 2;
    unsigned char* g  = (unsigned char*)p; p += (size_t)NN * 128;     // fp8 e4m3
    unsigned short* xf8 = (unsigned short*)p; p += (size_t)NN * 128;  // fp8 e4m3 copy of x
    unsigned short* wb1 = (unsigned short*)p; p += 65536 * 2;
    unsigned short* wb2 = (unsigned short*)p; p += 65536 * 2;
    int* deg  = (int*)p; p += (size_t)NN * 4;
    int* off  = (int*)p; p += (size_t)NN * 4;
    int* csr  = (int*)p; p += (size_t)NE * 4;
    int* bcnt = (int*)p; p += NB * 4;
    int* boff = (int*)p; p += (NB + 1) * 4;
    int* bcur = (int*)p; p += NB * 4;
    if (ws_size < (size_t)(p - (char*)d_ws)) return;
    unsigned int* pairs = (unsigned int*)h;       // overlay: dead before gemm1 writes h
    unsigned short* partial = (unsigned short*)axb; // overlay: axb dead after gemm1 reads it

    hipMemsetAsync(bcnt, 0, NB * 4, stream);
    k_prep<<<25384, 256, 0, stream>>>(x, W1l, W1r, W2l, W2r, ei, axb, xf8, wb1, wb2, bcnt);
    k_bscan<<<1, NB, 0, stream>>>(bcnt, boff, bcur);
    k_bscatter<<<NCH, 256, 0, stream>>>(ei, bcur, pairs);
    k_build<<<NB, 256, 0, stream>>>(pairs, boff, off, deg, csr);
    k_agg1<<<NN * 64 / 256, 256, 0, stream>>>((const uint2*)xf8, off, deg, csr, axb);
    k_gemm1<<<NCHUNK * 4, 256, 0, stream>>>((const unsigned short*)axb, wb1, b1, h);
    k_gemm2<<<NCHUNK * 4, 256, 0, stream>>>(h, wb2, b2, g, partial);
    k_agg2<<<25000, 256, 0, stream>>>((const uint2*)g, off, deg, csr, partial, out);
}

// Round 2
// 371.759 us; speedup vs baseline: 1.0042x; 1.0042x over previous
//
#include <hip/hip_runtime.h>
#include <hip/hip_bf16.h>
#include <hip/hip_fp16.h>

#define NN 100000
#define NE 1600000
#define NCHUNK ((NN + 127) / 128)   // 782 (gemm row chunks of 128)
#define NPB 512                      // nodes per bucket (pow2, shift 9)
#define NB 256                       // bucket slots (196 active)
#define CHUNK 8192                   // edges per bscatter block
#define NCH ((NE + CHUNK - 1) / CHUNK)  // 196

typedef __attribute__((ext_vector_type(8))) short short8;
typedef __attribute__((ext_vector_type(4))) float float4v;
typedef __attribute__((ext_vector_type(2))) float float2v;

__device__ __forceinline__ unsigned short f2bf(float f) {
    unsigned int b = __float_as_uint(f);
    return (unsigned short)((b + 0x7fffu + ((b >> 16) & 1u)) >> 16);
}
__device__ __forceinline__ unsigned int pack_bf16(float lo, float hi) {
    return (unsigned int)f2bf(lo) | ((unsigned int)f2bf(hi) << 16);
}
// 8 fp8 (e4m3) in a uint2 -> accumulate into a[0..7]
__device__ __forceinline__ void addp8(float* a, uint2 u) {
    float2v f;
    f = __builtin_amdgcn_cvt_pk_f32_fp8(u.x, false); a[0] += f.x; a[1] += f.y;
    f = __builtin_amdgcn_cvt_pk_f32_fp8(u.x, true);  a[2] += f.x; a[3] += f.y;
    f = __builtin_amdgcn_cvt_pk_f32_fp8(u.y, false); a[4] += f.x; a[5] += f.y;
    f = __builtin_amdgcn_cvt_pk_f32_fp8(u.y, true);  a[6] += f.x; a[7] += f.y;
}
__device__ __forceinline__ unsigned char f2fp8(float v) {
    int r = __builtin_amdgcn_cvt_pk_fp8_f32(v, v, 0, false);
    return (unsigned char)(r & 0xff);
}
__device__ __forceinline__ unsigned short pack2fp8(float lo, float hi) {
    int r = __builtin_amdgcn_cvt_pk_fp8_f32(lo, hi, 0, false);
    return (unsigned short)(r & 0xffff);
}
__device__ __forceinline__ float h2f(unsigned short u) {
    return __half2float(__ushort_as_half(u));
}

// ---- fused prep: xconv (blocks 0..24999), wconv (25000..25127), bcount (25128..25383) ----
__global__ void k_prep(const float* x, const float* W1l, const float* W1r,
                       const float* W2l, const float* W2r, const int* ei,
                       unsigned int* axb_u, unsigned short* xf8, unsigned short* wb1,
                       unsigned short* wb2, int* bcnt) {
    __shared__ int hh[NB];
    int b = blockIdx.x, t = threadIdx.x;
    if (b < 25000) {
        int tt = b * 256 + t;
        int node = tt >> 6, i = tt & 63;
        float2 v = ((const float2*)x)[tt];
        axb_u[(size_t)node * 128 + 64 + i] = pack_bf16(v.x, v.y);
        xf8[(size_t)node * 64 + i] = pack2fp8(v.x, v.y);
    } else if (b < 25128) {
        int i = (b - 25000) * 256 + t;        // < 32768
        int r1 = i >> 7, c1 = i & 127;        // W1l/W1r are 256x128
        wb1[r1 * 256 + c1]       = f2bf(W1l[i]);
        wb1[r1 * 256 + 128 + c1] = f2bf(W1r[i]);
        wb2[i]         = f2bf(W2l[i]);        // 128x256, k contiguous
        wb2[32768 + i] = f2bf(W2r[i]);
    } else {
        hh[t] = 0;
        __syncthreads();
        int e0 = (b - 25128) * 6250;          // 256 * 6250 = NE exactly
        for (int e = e0 + t; e < e0 + 6250; e += 256)
            atomicAdd(&hh[ei[NE + e] >> 9], 1);
        __syncthreads();
        if (hh[t]) atomicAdd(&bcnt[t], hh[t]);
    }
}

__global__ void k_bscan(const int* bcnt, int* boff, int* bcur) {
    __shared__ int s[NB];
    int t = threadIdx.x;
    int v = bcnt[t];
    s[t] = v;
    __syncthreads();
    for (int d = 1; d < NB; d <<= 1) {
        int val = (t >= d) ? s[t - d] : 0;
        __syncthreads();
        s[t] += val;
        __syncthreads();
    }
    boff[t + 1] = s[t];
    if (t == 0) boff[0] = 0;
    bcur[t] = s[t] - v;   // exclusive
}

// pairs packed: bits[0:17)=row, bits[17:26)=col&511 (bucket-local)
__global__ __launch_bounds__(256) void k_bscatter(const int* ei, int* bcur, unsigned int* pairs) {
    __shared__ unsigned int buf[CHUNK];   // 32 KB
    __shared__ int cnt[NB];
    __shared__ int lbase[NB];
    __shared__ int lcur[NB];
    __shared__ int gpos[NB];
    int t = threadIdx.x;
    int e0 = blockIdx.x * CHUNK;
    int nedge = NE - e0; if (nedge > CHUNK) nedge = CHUNK;
    cnt[t] = 0;
    __syncthreads();
    for (int i = t; i < nedge; i += 256)
        atomicAdd(&cnt[ei[NE + e0 + i] >> 9], 1);
    __syncthreads();
    int v = cnt[t];
    lcur[t] = v;
    __syncthreads();
    for (int d = 1; d < NB; d <<= 1) {
        int val = (t >= d) ? lcur[t - d] : 0;
        __syncthreads();
        lcur[t] += val;
        __syncthreads();
    }
    lbase[t] = lcur[t] - v;
    gpos[t] = atomicAdd(&bcur[t], v);
    __syncthreads();
    lcur[t] = lbase[t];
    __syncthreads();
    for (int i = t; i < nedge; i += 256) {
        int r = ei[e0 + i], c = ei[NE + e0 + i];
        int b = c >> 9;
        int p = atomicAdd(&lcur[b], 1);
        buf[p] = (unsigned)r | ((unsigned)(c & 511) << 17);
    }
    __syncthreads();
    // coalesced flush: wave wv handles buckets wv, wv+4, ...; lanes stride inside
    int wv = t >> 6, lane = t & 63;
    for (int b = wv; b < NB; b += 4) {
        int n = cnt[b], lb = lbase[b], gp = gpos[b];
        for (int i = lane; i < n; i += 64)
            pairs[gp + i] = buf[lb + i];
    }
}

__global__ __launch_bounds__(256) void k_build(const unsigned int* pairs, const int* boff,
                                               int* off, int* deg, int* csr) {
    __shared__ int ldeg[NPB];
    __shared__ int lcur[NPB];
    __shared__ int sscan[256];
    int b = blockIdx.x;
    int nbase = b * NPB;
    if (nbase >= NN) return;
    int t = threadIdx.x;
    int base = boff[b], cntb = boff[b + 1] - base;
    ldeg[t] = 0; ldeg[t + 256] = 0;
    __syncthreads();
    for (int i = t; i < cntb; i += 256) {
        unsigned int pr = pairs[base + i];
        atomicAdd(&ldeg[pr >> 17], 1);
    }
    __syncthreads();
    int d0 = ldeg[2 * t], d1 = ldeg[2 * t + 1];
    int v = d0 + d1;
    sscan[t] = v;
    __syncthreads();
    for (int d = 1; d < 256; d <<= 1) {
        int val = (t >= d) ? sscan[t - d] : 0;
        __syncthreads();
        sscan[t] += val;
        __syncthreads();
    }
    int ex = sscan[t] - v;
    lcur[2 * t] = ex; lcur[2 * t + 1] = ex + d0;
    __syncthreads();
    int nloc = NN - nbase; if (nloc > NPB) nloc = NPB;
    for (int ln = t; ln < nloc; ln += 256) {
        off[nbase + ln] = base + lcur[ln];
        deg[nbase + ln] = ldeg[ln];
    }
    __syncthreads();
    for (int i = t; i < cntb; i += 256) {
        unsigned int pr = pairs[base + i];
        int p = atomicAdd(&lcur[pr >> 17], 1);
        csr[base + p] = (int)(pr & 0x1FFFFu);
    }
}

// ---- agg1: mean of xf8 (fp8) over neighbors -> axb cols 0..127 (bf16) ----
// 4-deep unrolled gather: 16 independent row-loads in flight per wave
__global__ void k_agg1(const uint2* xf8, const int* off, const int* deg,
                       const int* csr, unsigned int* axb_w) {
    int wid = (blockIdx.x * 256 + threadIdx.x) >> 6;
    if (wid >= NN) return;
    int lane = threadIdx.x & 63;
    int sub = lane >> 4, l16 = lane & 15;
    int start = off[wid], d = deg[wid];
    const uint2* gp = xf8 + l16;   // row stride = 16 uint2 (128 B)
    float a[8] = {0.f, 0.f, 0.f, 0.f, 0.f, 0.f, 0.f, 0.f};
    int j = sub;
    for (; j + 12 < d; j += 16) {
        int n0 = csr[start + j];
        int n1 = csr[start + j + 4];
        int n2 = csr[start + j + 8];
        int n3 = csr[start + j + 12];
        uint2 u0 = gp[(size_t)n0 * 16];
        uint2 u1 = gp[(size_t)n1 * 16];
        uint2 u2 = gp[(size_t)n2 * 16];
        uint2 u3 = gp[(size_t)n3 * 16];
        addp8(a, u0); addp8(a, u1); addp8(a, u2); addp8(a, u3);
    }
    for (; j < d; j += 4) {
        int nb = csr[start + j];
        uint2 u = gp[(size_t)nb * 16];
        addp8(a, u);
    }
#pragma unroll
    for (int i = 0; i < 8; i++) {
        a[i] += __shfl_xor(a[i], 16, 64);
        a[i] += __shfl_xor(a[i], 32, 64);
    }
    if (sub == 0) {
        float inv = 1.0f / (float)(d > 0 ? d : 1);
        uint4 o;
        o.x = pack_bf16(a[0] * inv, a[1] * inv);
        o.y = pack_bf16(a[2] * inv, a[3] * inv);
        o.z = pack_bf16(a[4] * inv, a[5] * inv);
        o.w = pack_bf16(a[6] * inv, a[7] * inv);
        *(uint4*)(axb_w + (size_t)wid * 128 + (l16 << 2)) = o;
    }
}

// ---- agg2: out = partial(f16) + mean of g (fp8) over neighbors ----
// 4-deep unrolled gather; partial load hoisted above the gather loop
__global__ void k_agg2(const uint2* g, const int* off, const int* deg,
                       const int* csr, const unsigned short* partial, float* out) {
    int wid = (blockIdx.x * 256 + threadIdx.x) >> 6;
    if (wid >= NN) return;
    int lane = threadIdx.x & 63;
    int sub = lane >> 4, l16 = lane & 15;
    int start = off[wid], d = deg[wid];
    const uint2* gp = g + l16;   // row stride = 16 uint2 (128 B)
    uint4 pu;
    if (sub == 0)
        pu = *(const uint4*)(partial + (size_t)wid * 128 + (l16 << 3));
    float a[8] = {0.f, 0.f, 0.f, 0.f, 0.f, 0.f, 0.f, 0.f};
    int j = sub;
    for (; j + 12 < d; j += 16) {
        int n0 = csr[start + j];
        int n1 = csr[start + j + 4];
        int n2 = csr[start + j + 8];
        int n3 = csr[start + j + 12];
        uint2 u0 = gp[(size_t)n0 * 16];
        uint2 u1 = gp[(size_t)n1 * 16];
        uint2 u2 = gp[(size_t)n2 * 16];
        uint2 u3 = gp[(size_t)n3 * 16];
        addp8(a, u0); addp8(a, u1); addp8(a, u2); addp8(a, u3);
    }
    for (; j < d; j += 4) {
        int nb = csr[start + j];
        uint2 u = gp[(size_t)nb * 16];
        addp8(a, u);
    }
#pragma unroll
    for (int i = 0; i < 8; i++) {
        a[i] += __shfl_xor(a[i], 16, 64);
        a[i] += __shfl_xor(a[i], 32, 64);
    }
    if (sub == 0) {
        float inv = 1.0f / (float)(d > 0 ? d : 1);
        float4 c0, c1;
        c0.x = h2f(pu.x & 0xffff) + a[0] * inv; c0.y = h2f(pu.x >> 16) + a[1] * inv;
        c0.z = h2f(pu.y & 0xffff) + a[2] * inv; c0.w = h2f(pu.y >> 16) + a[3] * inv;
        c1.x = h2f(pu.z & 0xffff) + a[4] * inv; c1.y = h2f(pu.z >> 16) + a[5] * inv;
        c1.z = h2f(pu.w & 0xffff) + a[6] * inv; c1.w = h2f(pu.w >> 16) + a[7] * inv;
        float4* po = (float4*)(out + (size_t)wid * 128) + (l16 << 1);
        po[0] = c0; po[1] = c1;
    }
}

// ---- GEMM1 (col-split): block = 128 rows x 64 cols of relu(A@wb1^T + b1) -> H (bf16) ----
// grid = NCHUNK*4; cg = blockIdx&3 owns output cols [cg*64, cg*64+64)
// B slice in LDS: 64 rows x 264 ushorts (8-ushort pad -> per-row bank-group rotation)
#define BROW 264
__global__ __launch_bounds__(256, 4) void k_gemm1(const unsigned short* A, const unsigned short* wb,
                                                  const float* b1, unsigned short* H) {
    __shared__ unsigned short Bs[64 * BROW];   // 33 KB
    int t = threadIdx.x;
    int cg = blockIdx.x & 3, chunk = blockIdx.x >> 2;
    {
        const short8* src = (const short8*)(wb + (size_t)cg * 64 * 256);
        short8* dst = (short8*)Bs;   // 33 granules per row
#pragma unroll
        for (int i = 0; i < 8; i++) {
            int gi = i * 256 + t;             // 2048 granules of 16B
            int r = gi >> 5, c = gi & 31;
            dst[r * 33 + c] = src[gi];
        }
    }
    __syncthreads();
    int wv = t >> 6, lane = t & 63;
    int mrow = lane & 15, quad = lane >> 4;
    int base = chunk * 128 + wv * 32;
    if (base >= NN) return;
    float bias[4];
#pragma unroll
    for (int ctl = 0; ctl < 4; ctl++) bias[ctl] = b1[cg * 64 + ctl * 16 + mrow];
    float4v acc[2][4];
#pragma unroll
    for (int h = 0; h < 2; h++)
#pragma unroll
        for (int ctl = 0; ctl < 4; ctl++) acc[h][ctl] = (float4v)(0.0f);
    const short8* a0p = (const short8*)(A + (size_t)(base + mrow) * 256);
    const short8* a1p = (const short8*)(A + (size_t)(base + 16 + mrow) * 256);
#pragma unroll
    for (int kk = 0; kk < 8; kk++) {
        short8 a0 = a0p[kk * 4 + quad];
        short8 a1 = a1p[kk * 4 + quad];
        int koff = kk * 32 + quad * 8;
#pragma unroll
        for (int ctl = 0; ctl < 4; ctl++) {
            short8 b = *(const short8*)(Bs + (ctl * 16 + mrow) * BROW + koff);
            acc[0][ctl] = __builtin_amdgcn_mfma_f32_16x16x32_bf16(a0, b, acc[0][ctl], 0, 0, 0);
            acc[1][ctl] = __builtin_amdgcn_mfma_f32_16x16x32_bf16(a1, b, acc[1][ctl], 0, 0, 0);
        }
    }
#pragma unroll
    for (int ctl = 0; ctl < 4; ctl++) {
        int col = cg * 64 + ctl * 16 + mrow;
#pragma unroll
        for (int h = 0; h < 2; h++)
#pragma unroll
            for (int r = 0; r < 4; r++) {
                int node = base + h * 16 + quad * 4 + r;
                float v = acc[h][ctl][r] + bias[ctl];
                H[(size_t)node * 256 + col] = f2bf(fmaxf(v, 0.f));
            }
    }
}

// ---- GEMM2 (col-split): cg 0,1 -> g (fp8, cols 0..127); cg 2,3 -> partial f16 (+b2) ----
__global__ __launch_bounds__(256, 4) void k_gemm2(const unsigned short* A, const unsigned short* wb,
                                                  const float* b2, unsigned char* g,
                                                  unsigned short* partial) {
    __shared__ unsigned short Bs[64 * BROW];   // 33 KB
    int t = threadIdx.x;
    int cg = blockIdx.x & 3, chunk = blockIdx.x >> 2;
    {
        const short8* src = (const short8*)(wb + (size_t)cg * 64 * 256);
        short8* dst = (short8*)Bs;
#pragma unroll
        for (int i = 0; i < 8; i++) {
            int gi = i * 256 + t;
            int r = gi >> 5, c = gi & 31;
            dst[r * 33 + c] = src[gi];
        }
    }
    __syncthreads();
    int wv = t >> 6, lane = t & 63;
    int mrow = lane & 15, quad = lane >> 4;
    int base = chunk * 128 + wv * 32;
    if (base >= NN) return;
    float bias[4];
#pragma unroll
    for (int ctl = 0; ctl < 4; ctl++)
        bias[ctl] = (cg >= 2) ? b2[cg * 64 + ctl * 16 + mrow - 128] : 0.f;
    float4v acc[2][4];
#pragma unroll
    for (int h = 0; h < 2; h++)
#pragma unroll
        for (int ctl = 0; ctl < 4; ctl++) acc[h][ctl] = (float4v)(0.0f);
    const short8* a0p = (const short8*)(A + (size_t)(base + mrow) * 256);
    const short8* a1p = (const short8*)(A + (size_t)(base + 16 + mrow) * 256);
#pragma unroll
    for (int kk = 0; kk < 8; kk++) {
        short8 a0 = a0p[kk * 4 + quad];
        short8 a1 = a1p[kk * 4 + quad];
        int koff = kk * 32 + quad * 8;
#pragma unroll
        for (int ctl = 0; ctl < 4; ctl++) {
            short8 b = *(const short8*)(Bs + (ctl * 16 + mrow) * BROW + koff);
            acc[0][ctl] = __builtin_amdgcn_mfma_f32_16x16x32_bf16(a0, b, acc[0][ctl], 0, 0, 0);
            acc[1][ctl] = __builtin_amdgcn_mfma_f32_16x16x32_bf16(a1, b, acc[1][ctl], 0, 0, 0);
        }
    }
    if (cg < 2) {
#pragma unroll
        for (int ctl = 0; ctl < 4; ctl++) {
            int col = cg * 64 + ctl * 16 + mrow;   // in [0,128)
#pragma unroll
            for (int h = 0; h < 2; h++)
#pragma unroll
                for (int r = 0; r < 4; r++) {
                    int node = base + h * 16 + quad * 4 + r;
                    g[(size_t)node * 128 + col] = f2fp8(acc[h][ctl][r]);
                }
        }
    } else {
#pragma unroll
        for (int ctl = 0; ctl < 4; ctl++) {
            int pcol = cg * 64 + ctl * 16 + mrow - 128;   // in [0,128)
#pragma unroll
            for (int h = 0; h < 2; h++)
#pragma unroll
                for (int r = 0; r < 4; r++) {
                    int node = base + h * 16 + quad * 4 + r;
                    __half hf = __float2half(acc[h][ctl][r] + bias[ctl]);
                    partial[(size_t)node * 128 + pcol] = __half_as_ushort(hf);
                }
        }
    }
}

extern "C" void kernel_launch(void* const* d_in, const int* in_sizes, int n_in,
                              void* d_out, int out_size, void* d_ws, size_t ws_size,
                              hipStream_t stream) {
    const float* x   = (const float*)d_in[0];
    const int*   ei  = (const int*)d_in[1];
    const float* W1l = (const float*)d_in[2];
    const float* b1  = (const float*)d_in[3];
    const float* W1r = (const float*)d_in[4];
    const float* W2l = (const float*)d_in[5];
    const float* b2  = (const float*)d_in[6];
    const float* W2r = (const float*)d_in[7];
    float* out = (float*)d_out;

    char* p = (char*)d_ws;
    unsigned int* axb = (unsigned int*)p; p += (size_t)NN * 256 * 2;  // [agg(128) | x(128)] bf16
    unsigned short* h = (unsigned short*)p; p += (size_t)NN * 256 * 2;
    unsigned char* g  = (unsigned char*)p; p += (size_t)NN * 128;     // fp8 e4m3
    unsigned short* xf8 = (unsigned short*)p; p += (size_t)NN * 128;  // fp8 e4m3 copy of x
    unsigned short* wb1 = (unsigned short*)p; p += 65536 * 2;
    unsigned short* wb2 = (unsigned short*)p; p += 65536 * 2;
    int* deg  = (int*)p; p += (size_t)NN * 4;
    int* off  = (int*)p; p += (size_t)NN * 4;
    int* csr  = (int*)p; p += (size_t)NE * 4;
    int* bcnt = (int*)p; p += NB * 4;
    int* boff = (int*)p; p += (NB + 1) * 4;
    int* bcur = (int*)p; p += NB * 4;
    if (ws_size < (size_t)(p - (char*)d_ws)) return;
    unsigned int* pairs = (unsigned int*)h;       // overlay: dead before gemm1 writes h
    unsigned short* partial = (unsigned short*)axb; // overlay: axb dead after gemm1 reads it

    hipMemsetAsync(bcnt, 0, NB * 4, stream);
    k_prep<<<25384, 256, 0, stream>>>(x, W1l, W1r, W2l, W2r, ei, axb, xf8, wb1, wb2, bcnt);
    k_bscan<<<1, NB, 0, stream>>>(bcnt, boff, bcur);
    k_bscatter<<<NCH, 256, 0, stream>>>(ei, bcur, pairs);
    k_build<<<NB, 256, 0, stream>>>(pairs, boff, off, deg, csr);
    k_agg1<<<NN * 64 / 256, 256, 0, stream>>>((const uint2*)xf8, off, deg, csr, axb);
    k_gemm1<<<NCHUNK * 4, 256, 0, stream>>>((const unsigned short*)axb, wb1, b1, h);
    k_gemm2<<<NCHUNK * 4, 256, 0, stream>>>(h, wb2, b2, g, partial);
    k_agg2<<<25000, 256, 0, stream>>>((const uint2*)g, off, deg, csr, partial, out);
}

// Round 3
// 366.585 us; speedup vs baseline: 1.0184x; 1.0141x over previous
//
#include <hip/hip_runtime.h>
#include <hip/hip_bf16.h>
#include <hip/hip_fp16.h>

#define NN 100000
#define NE 1600000
#define NCHUNK ((NN + 127) / 128)   // 782 (gemm row chunks of 128)
#define NPB 512                      // nodes per bucket (pow2, shift 9)
#define NB 256                       // bucket slots (196 active)
#define CHUNK 8192                   // edges per bscatter block
#define NCH ((NE + CHUNK - 1) / CHUNK)  // 196
#define AGGW 8192                    // persistent agg waves (2048 blocks x 4)

typedef __attribute__((ext_vector_type(8))) short short8;
typedef __attribute__((ext_vector_type(4))) float float4v;
typedef __attribute__((ext_vector_type(2))) float float2v;

__device__ __forceinline__ unsigned short f2bf(float f) {
    unsigned int b = __float_as_uint(f);
    return (unsigned short)((b + 0x7fffu + ((b >> 16) & 1u)) >> 16);
}
__device__ __forceinline__ unsigned int pack_bf16(float lo, float hi) {
    return (unsigned int)f2bf(lo) | ((unsigned int)f2bf(hi) << 16);
}
// 8 fp8 (e4m3) in a uint2 -> accumulate into a[0..7]
__device__ __forceinline__ void addp8(float* a, uint2 u) {
    float2v f;
    f = __builtin_amdgcn_cvt_pk_f32_fp8(u.x, false); a[0] += f.x; a[1] += f.y;
    f = __builtin_amdgcn_cvt_pk_f32_fp8(u.x, true);  a[2] += f.x; a[3] += f.y;
    f = __builtin_amdgcn_cvt_pk_f32_fp8(u.y, false); a[4] += f.x; a[5] += f.y;
    f = __builtin_amdgcn_cvt_pk_f32_fp8(u.y, true);  a[6] += f.x; a[7] += f.y;
}
__device__ __forceinline__ unsigned char f2fp8(float v) {
    int r = __builtin_amdgcn_cvt_pk_fp8_f32(v, v, 0, false);
    return (unsigned char)(r & 0xff);
}
__device__ __forceinline__ unsigned short pack2fp8(float lo, float hi) {
    int r = __builtin_amdgcn_cvt_pk_fp8_f32(lo, hi, 0, false);
    return (unsigned short)(r & 0xffff);
}
__device__ __forceinline__ float h2f(unsigned short u) {
    return __half2float(__ushort_as_half(u));
}

// ---- fused prep: xconv (blocks 0..24999), wconv (25000..25127), bcount (25128..25383) ----
__global__ void k_prep(const float* x, const float* W1l, const float* W1r,
                       const float* W2l, const float* W2r, const int* ei,
                       unsigned int* axb_u, unsigned short* xf8, unsigned short* wb1,
                       unsigned short* wb2, int* bcnt) {
    __shared__ int hh[NB];
    int b = blockIdx.x, t = threadIdx.x;
    if (b < 25000) {
        int tt = b * 256 + t;
        int node = tt >> 6, i = tt & 63;
        float2 v = ((const float2*)x)[tt];
        axb_u[(size_t)node * 128 + 64 + i] = pack_bf16(v.x, v.y);
        xf8[(size_t)node * 64 + i] = pack2fp8(v.x, v.y);
    } else if (b < 25128) {
        int i = (b - 25000) * 256 + t;        // < 32768
        int r1 = i >> 7, c1 = i & 127;        // W1l/W1r are 256x128
        wb1[r1 * 256 + c1]       = f2bf(W1l[i]);
        wb1[r1 * 256 + 128 + c1] = f2bf(W1r[i]);
        wb2[i]         = f2bf(W2l[i]);        // 128x256, k contiguous
        wb2[32768 + i] = f2bf(W2r[i]);
    } else {
        hh[t] = 0;
        __syncthreads();
        int e0 = (b - 25128) * 6250;          // 256 * 6250 = NE exactly
        for (int e = e0 + t; e < e0 + 6250; e += 256)
            atomicAdd(&hh[ei[NE + e] >> 9], 1);
        __syncthreads();
        if (hh[t]) atomicAdd(&bcnt[t], hh[t]);
    }
}

__global__ void k_bscan(const int* bcnt, int* boff, int* bcur) {
    __shared__ int s[NB];
    int t = threadIdx.x;
    int v = bcnt[t];
    s[t] = v;
    __syncthreads();
    for (int d = 1; d < NB; d <<= 1) {
        int val = (t >= d) ? s[t - d] : 0;
        __syncthreads();
        s[t] += val;
        __syncthreads();
    }
    boff[t + 1] = s[t];
    if (t == 0) boff[0] = 0;
    bcur[t] = s[t] - v;   // exclusive
}

// pairs packed: bits[0:17)=row, bits[17:26)=col&511 (bucket-local)
__global__ __launch_bounds__(256) void k_bscatter(const int* ei, int* bcur, unsigned int* pairs) {
    __shared__ unsigned int buf[CHUNK];   // 32 KB
    __shared__ int cnt[NB];
    __shared__ int lbase[NB];
    __shared__ int lcur[NB];
    __shared__ int gpos[NB];
    int t = threadIdx.x;
    int e0 = blockIdx.x * CHUNK;
    int nedge = NE - e0; if (nedge > CHUNK) nedge = CHUNK;
    cnt[t] = 0;
    __syncthreads();
    for (int i = t; i < nedge; i += 256)
        atomicAdd(&cnt[ei[NE + e0 + i] >> 9], 1);
    __syncthreads();
    int v = cnt[t];
    lcur[t] = v;
    __syncthreads();
    for (int d = 1; d < NB; d <<= 1) {
        int val = (t >= d) ? lcur[t - d] : 0;
        __syncthreads();
        lcur[t] += val;
        __syncthreads();
    }
    lbase[t] = lcur[t] - v;
    gpos[t] = atomicAdd(&bcur[t], v);
    __syncthreads();
    lcur[t] = lbase[t];
    __syncthreads();
    for (int i = t; i < nedge; i += 256) {
        int r = ei[e0 + i], c = ei[NE + e0 + i];
        int b = c >> 9;
        int p = atomicAdd(&lcur[b], 1);
        buf[p] = (unsigned)r | ((unsigned)(c & 511) << 17);
    }
    __syncthreads();
    // coalesced flush: wave wv handles buckets wv, wv+4, ...; lanes stride inside
    int wv = t >> 6, lane = t & 63;
    for (int b = wv; b < NB; b += 4) {
        int n = cnt[b], lb = lbase[b], gp = gpos[b];
        for (int i = lane; i < n; i += 64)
            pairs[gp + i] = buf[lb + i];
    }
}

__global__ __launch_bounds__(256) void k_build(const unsigned int* pairs, const int* boff,
                                               int* off, int* deg, int* csr) {
    __shared__ int ldeg[NPB];
    __shared__ int lcur[NPB];
    __shared__ int sscan[256];
    int b = blockIdx.x;
    int nbase = b * NPB;
    if (nbase >= NN) return;
    int t = threadIdx.x;
    int base = boff[b], cntb = boff[b + 1] - base;
    ldeg[t] = 0; ldeg[t + 256] = 0;
    __syncthreads();
    for (int i = t; i < cntb; i += 256) {
        unsigned int pr = pairs[base + i];
        atomicAdd(&ldeg[pr >> 17], 1);
    }
    __syncthreads();
    int d0 = ldeg[2 * t], d1 = ldeg[2 * t + 1];
    int v = d0 + d1;
    sscan[t] = v;
    __syncthreads();
    for (int d = 1; d < 256; d <<= 1) {
        int val = (t >= d) ? sscan[t - d] : 0;
        __syncthreads();
        sscan[t] += val;
        __syncthreads();
    }
    int ex = sscan[t] - v;
    lcur[2 * t] = ex; lcur[2 * t + 1] = ex + d0;
    __syncthreads();
    int nloc = NN - nbase; if (nloc > NPB) nloc = NPB;
    for (int ln = t; ln < nloc; ln += 256) {
        off[nbase + ln] = base + lcur[ln];
        deg[nbase + ln] = ldeg[ln];
    }
    __syncthreads();
    for (int i = t; i < cntb; i += 256) {
        unsigned int pr = pairs[base + i];
        int p = atomicAdd(&lcur[pr >> 17], 1);
        csr[base + p] = (int)(pr & 0x1FFFFu);
    }
}

// ---- agg1: persistent+pipelined mean of xf8 (fp8) -> axb cols 0..127 (bf16) ----
// Each wave owns nodes {gw, gw+AGGW, ...}. While node A's gathers are in flight,
// node B's csr-index loads and node C's off/deg loads are already issued.
__global__ __launch_bounds__(256) void k_agg1(const uint2* xf8, const int* off, const int* deg,
                                              const int* csr, unsigned int* axb_w) {
    int gw = (blockIdx.x * 256 + threadIdx.x) >> 6;
    int lane = threadIdx.x & 63;
    int sub = lane >> 4, l16 = lane & 15;
    const uint2* gp = xf8 + l16;   // row stride = 16 uint2 (128 B)
    uint2 z; z.x = 0u; z.y = 0u;

    int nA = gw;
    int offA = off[nA], degA = deg[nA];
    int nB = nA + AGGW;
    int offB = 0, degB = 0;
    if (nB < NN) { offB = off[nB]; degB = deg[nB]; }
    int jA = sub;
    int iA0 = csr[min(offA + jA,      NE - 1)];
    int iA1 = csr[min(offA + jA + 4,  NE - 1)];
    int iA2 = csr[min(offA + jA + 8,  NE - 1)];
    int iA3 = csr[min(offA + jA + 12, NE - 1)];

    while (true) {
        // 1) issue gathers for A (exec-masked by validity)
        uint2 u0 = (jA      < degA) ? gp[(size_t)iA0 * 16] : z;
        uint2 u1 = (jA + 4  < degA) ? gp[(size_t)iA1 * 16] : z;
        uint2 u2 = (jA + 8  < degA) ? gp[(size_t)iA2 * 16] : z;
        uint2 u3 = (jA + 12 < degA) ? gp[(size_t)iA3 * 16] : z;
        // 2) issue csr idx loads for B
        int jB = sub;
        int iB0 = 0, iB1 = 0, iB2 = 0, iB3 = 0;
        if (nB < NN) {
            iB0 = csr[min(offB + jB,      NE - 1)];
            iB1 = csr[min(offB + jB + 4,  NE - 1)];
            iB2 = csr[min(offB + jB + 8,  NE - 1)];
            iB3 = csr[min(offB + jB + 12, NE - 1)];
        }
        // 3) issue off/deg for C
        int nC = nB + AGGW;
        int offC = 0, degC = 0;
        if (nC < NN) { offC = off[nC]; degC = deg[nC]; }
        // 4) accumulate A
        float a[8] = {0.f, 0.f, 0.f, 0.f, 0.f, 0.f, 0.f, 0.f};
        addp8(a, u0); addp8(a, u1); addp8(a, u2); addp8(a, u3);
        // 5) tail for degA > 16 (serial, ~43% of nodes)
        for (int j = 16 + sub; j < degA; j += 4) {
            int nb = csr[offA + j];
            uint2 u = gp[(size_t)nb * 16];
            addp8(a, u);
        }
        // 6) reduce + store
#pragma unroll
        for (int i = 0; i < 8; i++) {
            a[i] += __shfl_xor(a[i], 16, 64);
            a[i] += __shfl_xor(a[i], 32, 64);
        }
        if (sub == 0) {
            float inv = 1.0f / (float)(degA > 0 ? degA : 1);
            uint4 o;
            o.x = pack_bf16(a[0] * inv, a[1] * inv);
            o.y = pack_bf16(a[2] * inv, a[3] * inv);
            o.z = pack_bf16(a[4] * inv, a[5] * inv);
            o.w = pack_bf16(a[6] * inv, a[7] * inv);
            *(uint4*)(axb_w + (size_t)nA * 128 + (l16 << 2)) = o;
        }
        // rotate pipeline
        nA = nB; offA = offB; degA = degB;
        iA0 = iB0; iA1 = iB1; iA2 = iB2; iA3 = iB3; jA = jB;
        nB = nC; offB = offC; degB = degC;
        if (nA >= NN) break;
    }
}

// ---- agg2: persistent+pipelined; out = partial(f16) + mean of g (fp8) ----
__global__ __launch_bounds__(256) void k_agg2(const uint2* g, const int* off, const int* deg,
                                              const int* csr, const unsigned short* partial,
                                              float* out) {
    int gw = (blockIdx.x * 256 + threadIdx.x) >> 6;
    int lane = threadIdx.x & 63;
    int sub = lane >> 4, l16 = lane & 15;
    const uint2* gp = g + l16;   // row stride = 16 uint2 (128 B)
    uint2 z; z.x = 0u; z.y = 0u;

    int nA = gw;
    int offA = off[nA], degA = deg[nA];
    int nB = nA + AGGW;
    int offB = 0, degB = 0;
    if (nB < NN) { offB = off[nB]; degB = deg[nB]; }
    int jA = sub;
    int iA0 = csr[min(offA + jA,      NE - 1)];
    int iA1 = csr[min(offA + jA + 4,  NE - 1)];
    int iA2 = csr[min(offA + jA + 8,  NE - 1)];
    int iA3 = csr[min(offA + jA + 12, NE - 1)];

    while (true) {
        // 1) issue gathers for A
        uint2 u0 = (jA      < degA) ? gp[(size_t)iA0 * 16] : z;
        uint2 u1 = (jA + 4  < degA) ? gp[(size_t)iA1 * 16] : z;
        uint2 u2 = (jA + 8  < degA) ? gp[(size_t)iA2 * 16] : z;
        uint2 u3 = (jA + 12 < degA) ? gp[(size_t)iA3 * 16] : z;
        // 2) issue csr idx loads for B
        int jB = sub;
        int iB0 = 0, iB1 = 0, iB2 = 0, iB3 = 0;
        if (nB < NN) {
            iB0 = csr[min(offB + jB,      NE - 1)];
            iB1 = csr[min(offB + jB + 4,  NE - 1)];
            iB2 = csr[min(offB + jB + 8,  NE - 1)];
            iB3 = csr[min(offB + jB + 12, NE - 1)];
        }
        // 3) issue off/deg for C
        int nC = nB + AGGW;
        int offC = 0, degC = 0;
        if (nC < NN) { offC = off[nC]; degC = deg[nC]; }
        // 4) hoisted partial load for A (overlaps gather wait)
        uint4 pu;
        if (sub == 0)
            pu = *(const uint4*)(partial + (size_t)nA * 128 + (l16 << 3));
        // 5) accumulate A
        float a[8] = {0.f, 0.f, 0.f, 0.f, 0.f, 0.f, 0.f, 0.f};
        addp8(a, u0); addp8(a, u1); addp8(a, u2); addp8(a, u3);
        // 6) tail for degA > 16
        for (int j = 16 + sub; j < degA; j += 4) {
            int nb = csr[offA + j];
            uint2 u = gp[(size_t)nb * 16];
            addp8(a, u);
        }
        // 7) reduce + store
#pragma unroll
        for (int i = 0; i < 8; i++) {
            a[i] += __shfl_xor(a[i], 16, 64);
            a[i] += __shfl_xor(a[i], 32, 64);
        }
        if (sub == 0) {
            float inv = 1.0f / (float)(degA > 0 ? degA : 1);
            float4 c0, c1;
            c0.x = h2f(pu.x & 0xffff) + a[0] * inv; c0.y = h2f(pu.x >> 16) + a[1] * inv;
            c0.z = h2f(pu.y & 0xffff) + a[2] * inv; c0.w = h2f(pu.y >> 16) + a[3] * inv;
            c1.x = h2f(pu.z & 0xffff) + a[4] * inv; c1.y = h2f(pu.z >> 16) + a[5] * inv;
            c1.z = h2f(pu.w & 0xffff) + a[6] * inv; c1.w = h2f(pu.w >> 16) + a[7] * inv;
            float4* po = (float4*)(out + (size_t)nA * 128) + (l16 << 1);
            po[0] = c0; po[1] = c1;
        }
        // rotate pipeline
        nA = nB; offA = offB; degA = degB;
        iA0 = iB0; iA1 = iB1; iA2 = iB2; iA3 = iB3; jA = jB;
        nB = nC; offB = offC; degB = degC;
        if (nA >= NN) break;
    }
}

// ---- GEMM1 (col-split, XCD-swizzled): 128 rows x 64 cols of relu(A@wb1^T + b1) -> H ----
// b = (c&7) | cg<<3 | (c>>3)<<5  => the 4 cg-blocks of chunk c share an XCD (b mod 8 equal)
// and are dispatch-adjacent there -> A-tile L2 reuse.
#define BROW 264
#define GGRID (32 * ((NCHUNK + 7) / 8))   // 32*98 = 3136
__global__ __launch_bounds__(256, 4) void k_gemm1(const unsigned short* A, const unsigned short* wb,
                                                  const float* b1, unsigned short* H) {
    __shared__ unsigned short Bs[64 * BROW];   // 33 KB
    int t = threadIdx.x;
    int b = blockIdx.x;
    int chunk = (b & 7) + ((b >> 5) << 3);
    int cg = (b >> 3) & 3;
    if (chunk >= NCHUNK) return;
    {
        const short8* src = (const short8*)(wb + (size_t)cg * 64 * 256);
        short8* dst = (short8*)Bs;   // 33 granules per row
#pragma unroll
        for (int i = 0; i < 8; i++) {
            int gi = i * 256 + t;             // 2048 granules of 16B
            int r = gi >> 5, c = gi & 31;
            dst[r * 33 + c] = src[gi];
        }
    }
    __syncthreads();
    int wv = t >> 6, lane = t & 63;
    int mrow = lane & 15, quad = lane >> 4;
    int base = chunk * 128 + wv * 32;
    if (base >= NN) return;
    float bias[4];
#pragma unroll
    for (int ctl = 0; ctl < 4; ctl++) bias[ctl] = b1[cg * 64 + ctl * 16 + mrow];
    float4v acc[2][4];
#pragma unroll
    for (int h = 0; h < 2; h++)
#pragma unroll
        for (int ctl = 0; ctl < 4; ctl++) acc[h][ctl] = (float4v)(0.0f);
    const short8* a0p = (const short8*)(A + (size_t)(base + mrow) * 256);
    const short8* a1p = (const short8*)(A + (size_t)(base + 16 + mrow) * 256);
#pragma unroll
    for (int kk = 0; kk < 8; kk++) {
        short8 a0 = a0p[kk * 4 + quad];
        short8 a1 = a1p[kk * 4 + quad];
        int koff = kk * 32 + quad * 8;
#pragma unroll
        for (int ctl = 0; ctl < 4; ctl++) {
            short8 bfr = *(const short8*)(Bs + (ctl * 16 + mrow) * BROW + koff);
            acc[0][ctl] = __builtin_amdgcn_mfma_f32_16x16x32_bf16(a0, bfr, acc[0][ctl], 0, 0, 0);
            acc[1][ctl] = __builtin_amdgcn_mfma_f32_16x16x32_bf16(a1, bfr, acc[1][ctl], 0, 0, 0);
        }
    }
#pragma unroll
    for (int ctl = 0; ctl < 4; ctl++) {
        int col = cg * 64 + ctl * 16 + mrow;
#pragma unroll
        for (int h = 0; h < 2; h++)
#pragma unroll
            for (int r = 0; r < 4; r++) {
                int node = base + h * 16 + quad * 4 + r;
                float v = acc[h][ctl][r] + bias[ctl];
                H[(size_t)node * 256 + col] = f2bf(fmaxf(v, 0.f));
            }
    }
}

// ---- GEMM2 (col-split, XCD-swizzled): cg 0,1 -> g (fp8); cg 2,3 -> partial f16 (+b2) ----
__global__ __launch_bounds__(256, 4) void k_gemm2(const unsigned short* A, const unsigned short* wb,
                                                  const float* b2, unsigned char* g,
                                                  unsigned short* partial) {
    __shared__ unsigned short Bs[64 * BROW];   // 33 KB
    int t = threadIdx.x;
    int b = blockIdx.x;
    int chunk = (b & 7) + ((b >> 5) << 3);
    int cg = (b >> 3) & 3;
    if (chunk >= NCHUNK) return;
    {
        const short8* src = (const short8*)(wb + (size_t)cg * 64 * 256);
        short8* dst = (short8*)Bs;
#pragma unroll
        for (int i = 0; i < 8; i++) {
            int gi = i * 256 + t;
            int r = gi >> 5, c = gi & 31;
            dst[r * 33 + c] = src[gi];
        }
    }
    __syncthreads();
    int wv = t >> 6, lane = t & 63;
    int mrow = lane & 15, quad = lane >> 4;
    int base = chunk * 128 + wv * 32;
    if (base >= NN) return;
    float bias[4];
#pragma unroll
    for (int ctl = 0; ctl < 4; ctl++)
        bias[ctl] = (cg >= 2) ? b2[cg * 64 + ctl * 16 + mrow - 128] : 0.f;
    float4v acc[2][4];
#pragma unroll
    for (int h = 0; h < 2; h++)
#pragma unroll
        for (int ctl = 0; ctl < 4; ctl++) acc[h][ctl] = (float4v)(0.0f);
    const short8* a0p = (const short8*)(A + (size_t)(base + mrow) * 256);
    const short8* a1p = (const short8*)(A + (size_t)(base + 16 + mrow) * 256);
#pragma unroll
    for (int kk = 0; kk < 8; kk++) {
        short8 a0 = a0p[kk * 4 + quad];
        short8 a1 = a1p[kk * 4 + quad];
        int koff = kk * 32 + quad * 8;
#pragma unroll
        for (int ctl = 0; ctl < 4; ctl++) {
            short8 bfr = *(const short8*)(Bs + (ctl * 16 + mrow) * BROW + koff);
            acc[0][ctl] = __builtin_amdgcn_mfma_f32_16x16x32_bf16(a0, bfr, acc[0][ctl], 0, 0, 0);
            acc[1][ctl] = __builtin_amdgcn_mfma_f32_16x16x32_bf16(a1, bfr, acc[1][ctl], 0, 0, 0);
        }
    }
    if (cg < 2) {
#pragma unroll
        for (int ctl = 0; ctl < 4; ctl++) {
            int col = cg * 64 + ctl * 16 + mrow;   // in [0,128)
#pragma unroll
            for (int h = 0; h < 2; h++)
#pragma unroll
                for (int r = 0; r < 4; r++) {
                    int node = base + h * 16 + quad * 4 + r;
                    g[(size_t)node * 128 + col] = f2fp8(acc[h][ctl][r]);
                }
        }
    } else {
#pragma unroll
        for (int ctl = 0; ctl < 4; ctl++) {
            int pcol = cg * 64 + ctl * 16 + mrow - 128;   // in [0,128)
#pragma unroll
            for (int h = 0; h < 2; h++)
#pragma unroll
                for (int r = 0; r < 4; r++) {
                    int node = base + h * 16 + quad * 4 + r;
                    __half hf = __float2half(acc[h][ctl][r] + bias[ctl]);
                    partial[(size_t)node * 128 + pcol] = __half_as_ushort(hf);
                }
        }
    }
}

extern "C" void kernel_launch(void* const* d_in, const int* in_sizes, int n_in,
                              void* d_out, int out_size, void* d_ws, size_t ws_size,
                              hipStream_t stream) {
    const float* x   = (const float*)d_in[0];
    const int*   ei  = (const int*)d_in[1];
    const float* W1l = (const float*)d_in[2];
    const float* b1  = (const float*)d_in[3];
    const float* W1r = (const float*)d_in[4];
    const float* W2l = (const float*)d_in[5];
    const float* b2  = (const float*)d_in[6];
    const float* W2r = (const float*)d_in[7];
    float* out = (float*)d_out;

    char* p = (char*)d_ws;
    unsigned int* axb = (unsigned int*)p; p += (size_t)NN * 256 * 2;  // [agg(128) | x(128)] bf16
    unsigned short* h = (unsigned short*)p; p += (size_t)NN * 256 * 2;
    unsigned char* g  = (unsigned char*)p; p += (size_t)NN * 128;     // fp8 e4m3
    unsigned short* xf8 = (unsigned short*)p; p += (size_t)NN * 128;  // fp8 e4m3 copy of x
    unsigned short* wb1 = (unsigned short*)p; p += 65536 * 2;
    unsigned short* wb2 = (unsigned short*)p; p += 65536 * 2;
    int* deg  = (int*)p; p += (size_t)NN * 4;
    int* off  = (int*)p; p += (size_t)NN * 4;
    int* csr  = (int*)p; p += (size_t)NE * 4;
    int* bcnt = (int*)p; p += NB * 4;
    int* boff = (int*)p; p += (NB + 1) * 4;
    int* bcur = (int*)p; p += NB * 4;
    if (ws_size < (size_t)(p - (char*)d_ws)) return;
    unsigned int* pairs = (unsigned int*)h;       // overlay: dead before gemm1 writes h
    unsigned short* partial = (unsigned short*)axb; // overlay: axb dead after gemm1 reads it

    hipMemsetAsync(bcnt, 0, NB * 4, stream);
    k_prep<<<25384, 256, 0, stream>>>(x, W1l, W1r, W2l, W2r, ei, axb, xf8, wb1, wb2, bcnt);
    k_bscan<<<1, NB, 0, stream>>>(bcnt, boff, bcur);
    k_bscatter<<<NCH, 256, 0, stream>>>(ei, bcur, pairs);
    k_build<<<NB, 256, 0, stream>>>(pairs, boff, off, deg, csr);
    k_agg1<<<AGGW / 4, 256, 0, stream>>>((const uint2*)xf8, off, deg, csr, axb);
    k_gemm1<<<GGRID, 256, 0, stream>>>((const unsigned short*)axb, wb1, b1, h);
    k_gemm2<<<GGRID, 256, 0, stream>>>(h, wb2, b2, g, partial);
    k_agg2<<<AGGW / 4, 256, 0, stream>>>((const uint2*)g, off, deg, csr, partial, out);
}

// Round 4
// 356.109 us; speedup vs baseline: 1.0483x; 1.0294x over previous
//
#include <hip/hip_runtime.h>
#include <hip/hip_bf16.h>
#include <hip/hip_fp16.h>

#define NN 100000
#define NE 1600000
#define NCHUNK ((NN + 127) / 128)   // 782 (gemm row chunks of 128)
#define NPB 512                      // nodes per bucket (pow2, shift 9)
#define NB 256                       // bucket slots (196 active)
#define CHUNK 8192                   // edges per bscatter block
#define NCH ((NE + CHUNK - 1) / CHUNK)  // 196

typedef __attribute__((ext_vector_type(8))) short short8;
typedef __attribute__((ext_vector_type(4))) float float4v;
typedef __attribute__((ext_vector_type(2))) float float2v;

__device__ __forceinline__ unsigned short f2bf(float f) {
    unsigned int b = __float_as_uint(f);
    return (unsigned short)((b + 0x7fffu + ((b >> 16) & 1u)) >> 16);
}
__device__ __forceinline__ unsigned int pack_bf16(float lo, float hi) {
    return (unsigned int)f2bf(lo) | ((unsigned int)f2bf(hi) << 16);
}
// 8 fp8 (e4m3) in a uint2 -> accumulate into a[0..7]
__device__ __forceinline__ void addp8(float* a, uint2 u) {
    float2v f;
    f = __builtin_amdgcn_cvt_pk_f32_fp8(u.x, false); a[0] += f.x; a[1] += f.y;
    f = __builtin_amdgcn_cvt_pk_f32_fp8(u.x, true);  a[2] += f.x; a[3] += f.y;
    f = __builtin_amdgcn_cvt_pk_f32_fp8(u.y, false); a[4] += f.x; a[5] += f.y;
    f = __builtin_amdgcn_cvt_pk_f32_fp8(u.y, true);  a[6] += f.x; a[7] += f.y;
}
__device__ __forceinline__ unsigned char f2fp8(float v) {
    int r = __builtin_amdgcn_cvt_pk_fp8_f32(v, v, 0, false);
    return (unsigned char)(r & 0xff);
}
__device__ __forceinline__ unsigned short pack2fp8(float lo, float hi) {
    int r = __builtin_amdgcn_cvt_pk_fp8_f32(lo, hi, 0, false);
    return (unsigned short)(r & 0xffff);
}
__device__ __forceinline__ float h2f(unsigned short u) {
    return __half2float(__ushort_as_half(u));
}

// ---- fused prep: xconv (blocks 0..3124, 8 segs each), wconv (3125..3252), bcount (3253..3508) ----
__global__ void k_prep(const float* x, const float* W1l, const float* W1r,
                       const float* W2l, const float* W2r, const int* ei,
                       unsigned int* axb_u, unsigned short* xf8, unsigned short* wb1,
                       unsigned short* wb2, int* bcnt) {
    __shared__ int hh[NB];
    int b = blockIdx.x, t = threadIdx.x;
    if (b < 3125) {
#pragma unroll
        for (int k = 0; k < 8; k++) {
            int tt = b * 2048 + k * 256 + t;      // < 6.4M = NN*64
            int node = tt >> 6, i = tt & 63;
            float2 v = ((const float2*)x)[tt];
            axb_u[(size_t)node * 128 + 64 + i] = pack_bf16(v.x, v.y);
            xf8[(size_t)node * 64 + i] = pack2fp8(v.x, v.y);
        }
    } else if (b < 3253) {
        int i = (b - 3125) * 256 + t;         // < 32768
        int r1 = i >> 7, c1 = i & 127;        // W1l/W1r are 256x128
        wb1[r1 * 256 + c1]       = f2bf(W1l[i]);
        wb1[r1 * 256 + 128 + c1] = f2bf(W1r[i]);
        wb2[i]         = f2bf(W2l[i]);        // 128x256, k contiguous
        wb2[32768 + i] = f2bf(W2r[i]);
    } else {
        hh[t] = 0;
        __syncthreads();
        int e0 = (b - 3253) * 6250;           // 256 * 6250 = NE exactly
        for (int e = e0 + t; e < e0 + 6250; e += 256)
            atomicAdd(&hh[ei[NE + e] >> 9], 1);
        __syncthreads();
        if (hh[t]) atomicAdd(&bcnt[t], hh[t]);
    }
}

__global__ void k_bscan(const int* bcnt, int* boff, int* bcur) {
    __shared__ int s[NB];
    int t = threadIdx.x;
    int v = bcnt[t];
    s[t] = v;
    __syncthreads();
    for (int d = 1; d < NB; d <<= 1) {
        int val = (t >= d) ? s[t - d] : 0;
        __syncthreads();
        s[t] += val;
        __syncthreads();
    }
    boff[t + 1] = s[t];
    if (t == 0) boff[0] = 0;
    bcur[t] = s[t] - v;   // exclusive
}

// pairs packed: bits[0:17)=row, bits[17:26)=col&511 (bucket-local)
__global__ __launch_bounds__(256) void k_bscatter(const int* ei, int* bcur, unsigned int* pairs) {
    __shared__ unsigned int buf[CHUNK];   // 32 KB
    __shared__ int cnt[NB];
    __shared__ int lbase[NB];
    __shared__ int lcur[NB];
    __shared__ int gpos[NB];
    int t = threadIdx.x;
    int e0 = blockIdx.x * CHUNK;
    int nedge = NE - e0; if (nedge > CHUNK) nedge = CHUNK;
    cnt[t] = 0;
    __syncthreads();
    for (int i = t; i < nedge; i += 256)
        atomicAdd(&cnt[ei[NE + e0 + i] >> 9], 1);
    __syncthreads();
    int v = cnt[t];
    lcur[t] = v;
    __syncthreads();
    for (int d = 1; d < NB; d <<= 1) {
        int val = (t >= d) ? lcur[t - d] : 0;
        __syncthreads();
        lcur[t] += val;
        __syncthreads();
    }
    lbase[t] = lcur[t] - v;
    gpos[t] = atomicAdd(&bcur[t], v);
    __syncthreads();
    lcur[t] = lbase[t];
    __syncthreads();
    for (int i = t; i < nedge; i += 256) {
        int r = ei[e0 + i], c = ei[NE + e0 + i];
        int b = c >> 9;
        int p = atomicAdd(&lcur[b], 1);
        buf[p] = (unsigned)r | ((unsigned)(c & 511) << 17);
    }
    __syncthreads();
    // coalesced flush: wave wv handles buckets wv, wv+4, ...; lanes stride inside
    int wv = t >> 6, lane = t & 63;
    for (int b = wv; b < NB; b += 4) {
        int n = cnt[b], lb = lbase[b], gp = gpos[b];
        for (int i = lane; i < n; i += 64)
            pairs[gp + i] = buf[lb + i];
    }
}

// builds CSR; additionally writes dense first-16 neighbor table csr16[n][16] (if non-null)
__global__ __launch_bounds__(256) void k_build(const unsigned int* pairs, const int* boff,
                                               int* off, int* deg, int* csr, int* csr16) {
    __shared__ int ldeg[NPB];
    __shared__ int lcur[NPB];
    __shared__ int lini[NPB];
    __shared__ int sscan[256];
    int b = blockIdx.x;
    int nbase = b * NPB;
    if (nbase >= NN) return;
    int t = threadIdx.x;
    int base = boff[b], cntb = boff[b + 1] - base;
    ldeg[t] = 0; ldeg[t + 256] = 0;
    __syncthreads();
    for (int i = t; i < cntb; i += 256) {
        unsigned int pr = pairs[base + i];
        atomicAdd(&ldeg[pr >> 17], 1);
    }
    __syncthreads();
    int d0 = ldeg[2 * t], d1 = ldeg[2 * t + 1];
    int v = d0 + d1;
    sscan[t] = v;
    __syncthreads();
    for (int d = 1; d < 256; d <<= 1) {
        int val = (t >= d) ? sscan[t - d] : 0;
        __syncthreads();
        sscan[t] += val;
        __syncthreads();
    }
    int ex = sscan[t] - v;
    lcur[2 * t] = ex;      lcur[2 * t + 1] = ex + d0;
    lini[2 * t] = ex;      lini[2 * t + 1] = ex + d0;
    __syncthreads();
    int nloc = NN - nbase; if (nloc > NPB) nloc = NPB;
    for (int ln = t; ln < nloc; ln += 256) {
        off[nbase + ln] = base + lcur[ln];
        deg[nbase + ln] = ldeg[ln];
    }
    __syncthreads();
    if (csr16) {
        for (int i = t; i < cntb; i += 256) {
            unsigned int pr = pairs[base + i];
            int nd = pr >> 17;
            int p = atomicAdd(&lcur[nd], 1);
            int src = (int)(pr & 0x1FFFFu);
            csr[base + p] = src;
            int rk = p - lini[nd];
            if (rk < 16) csr16[(size_t)(nbase + nd) * 16 + rk] = src;
        }
    } else {
        for (int i = t; i < cntb; i += 256) {
            unsigned int pr = pairs[base + i];
            int p = atomicAdd(&lcur[pr >> 17], 1);
            csr[base + p] = (int)(pr & 0x1FFFFu);
        }
    }
}

// ---- agg1: mean of xf8 (fp8) over neighbors -> axb cols 0..127 (bf16) ----
// fast path: dense csr16 -> indices with no dependent hops; tail via csr
__global__ __launch_bounds__(512) void k_agg1(const uint2* xf8, const int* off, const int* deg,
                                              const int* csr, const int* csr16,
                                              unsigned int* axb_w) {
    int wid = (blockIdx.x * 512 + threadIdx.x) >> 6;
    if (wid >= NN) return;
    int lane = threadIdx.x & 63;
    int sub = lane >> 4, l16 = lane & 15;
    int start = off[wid], d = deg[wid];
    const uint2* gp = xf8 + l16;   // row stride = 16 uint2 (128 B)
    uint2 z; z.x = 0u; z.y = 0u;
    float a[8] = {0.f, 0.f, 0.f, 0.f, 0.f, 0.f, 0.f, 0.f};
    int j;
    if (csr16) {
        int e16 = csr16[(size_t)wid * 16 + l16];   // one 64B line, broadcast over subs
#pragma unroll
        for (int r = 0; r < 4; r++) {
            int rk = (r << 2) | sub;
            int idx = __shfl(e16, rk, 64);
            uint2 u = (rk < d) ? gp[(size_t)idx * 16] : z;
            addp8(a, u);
        }
        j = 16 + sub;
    } else {
        j = sub;
    }
    for (; j + 4 < d; j += 8) {
        int n0 = csr[start + j];
        int n1 = csr[start + j + 4];
        uint2 u0 = gp[(size_t)n0 * 16];
        uint2 u1 = gp[(size_t)n1 * 16];
        addp8(a, u0); addp8(a, u1);
    }
    if (j < d) {
        int nb = csr[start + j];
        uint2 u = gp[(size_t)nb * 16];
        addp8(a, u);
    }
#pragma unroll
    for (int i = 0; i < 8; i++) {
        a[i] += __shfl_xor(a[i], 16, 64);
        a[i] += __shfl_xor(a[i], 32, 64);
    }
    if (sub == 0) {
        float inv = 1.0f / (float)(d > 0 ? d : 1);
        uint4 o;
        o.x = pack_bf16(a[0] * inv, a[1] * inv);
        o.y = pack_bf16(a[2] * inv, a[3] * inv);
        o.z = pack_bf16(a[4] * inv, a[5] * inv);
        o.w = pack_bf16(a[6] * inv, a[7] * inv);
        *(uint4*)(axb_w + (size_t)wid * 128 + (l16 << 2)) = o;
    }
}

// ---- agg2: out = partial(f16) + mean of g (fp8) over neighbors ----
__global__ __launch_bounds__(512) void k_agg2(const uint2* g, const int* off, const int* deg,
                                              const int* csr, const int* csr16,
                                              const unsigned short* partial, float* out) {
    int wid = (blockIdx.x * 512 + threadIdx.x) >> 6;
    if (wid >= NN) return;
    int lane = threadIdx.x & 63;
    int sub = lane >> 4, l16 = lane & 15;
    int start = off[wid], d = deg[wid];
    const uint2* gp = g + l16;   // row stride = 16 uint2 (128 B)
    uint2 z; z.x = 0u; z.y = 0u;
    uint4 pu;
    if (sub == 0)
        pu = *(const uint4*)(partial + (size_t)wid * 128 + (l16 << 3));
    float a[8] = {0.f, 0.f, 0.f, 0.f, 0.f, 0.f, 0.f, 0.f};
    int j;
    if (csr16) {
        int e16 = csr16[(size_t)wid * 16 + l16];
#pragma unroll
        for (int r = 0; r < 4; r++) {
            int rk = (r << 2) | sub;
            int idx = __shfl(e16, rk, 64);
            uint2 u = (rk < d) ? gp[(size_t)idx * 16] : z;
            addp8(a, u);
        }
        j = 16 + sub;
    } else {
        j = sub;
    }
    for (; j + 4 < d; j += 8) {
        int n0 = csr[start + j];
        int n1 = csr[start + j + 4];
        uint2 u0 = gp[(size_t)n0 * 16];
        uint2 u1 = gp[(size_t)n1 * 16];
        addp8(a, u0); addp8(a, u1);
    }
    if (j < d) {
        int nb = csr[start + j];
        uint2 u = gp[(size_t)nb * 16];
        addp8(a, u);
    }
#pragma unroll
    for (int i = 0; i < 8; i++) {
        a[i] += __shfl_xor(a[i], 16, 64);
        a[i] += __shfl_xor(a[i], 32, 64);
    }
    if (sub == 0) {
        float inv = 1.0f / (float)(d > 0 ? d : 1);
        float4 c0, c1;
        c0.x = h2f(pu.x & 0xffff) + a[0] * inv; c0.y = h2f(pu.x >> 16) + a[1] * inv;
        c0.z = h2f(pu.y & 0xffff) + a[2] * inv; c0.w = h2f(pu.y >> 16) + a[3] * inv;
        c1.x = h2f(pu.z & 0xffff) + a[4] * inv; c1.y = h2f(pu.z >> 16) + a[5] * inv;
        c1.z = h2f(pu.w & 0xffff) + a[6] * inv; c1.w = h2f(pu.w >> 16) + a[7] * inv;
        float4* po = (float4*)(out + (size_t)wid * 128) + (l16 << 1);
        po[0] = c0; po[1] = c1;
    }
}

// ---- GEMM1 (col-split, XCD-swizzled): 128 rows x 64 cols of relu(A@wb1^T + b1) -> H ----
// b = (c&7) | cg<<3 | (c>>3)<<5  => the 4 cg-blocks of chunk c share an XCD (b mod 8 equal)
#define BROW 264
#define GGRID (32 * ((NCHUNK + 7) / 8))   // 32*98 = 3136
__global__ __launch_bounds__(256, 4) void k_gemm1(const unsigned short* A, const unsigned short* wb,
                                                  const float* b1, unsigned short* H) {
    __shared__ unsigned short Bs[64 * BROW];   // 33 KB
    int t = threadIdx.x;
    int b = blockIdx.x;
    int chunk = (b & 7) + ((b >> 5) << 3);
    int cg = (b >> 3) & 3;
    if (chunk >= NCHUNK) return;
    {
        const short8* src = (const short8*)(wb + (size_t)cg * 64 * 256);
        short8* dst = (short8*)Bs;   // 33 granules per row
#pragma unroll
        for (int i = 0; i < 8; i++) {
            int gi = i * 256 + t;             // 2048 granules of 16B
            int r = gi >> 5, c = gi & 31;
            dst[r * 33 + c] = src[gi];
        }
    }
    __syncthreads();
    int wv = t >> 6, lane = t & 63;
    int mrow = lane & 15, quad = lane >> 4;
    int base = chunk * 128 + wv * 32;
    if (base >= NN) return;
    float bias[4];
#pragma unroll
    for (int ctl = 0; ctl < 4; ctl++) bias[ctl] = b1[cg * 64 + ctl * 16 + mrow];
    float4v acc[2][4];
#pragma unroll
    for (int h = 0; h < 2; h++)
#pragma unroll
        for (int ctl = 0; ctl < 4; ctl++) acc[h][ctl] = (float4v)(0.0f);
    const short8* a0p = (const short8*)(A + (size_t)(base + mrow) * 256);
    const short8* a1p = (const short8*)(A + (size_t)(base + 16 + mrow) * 256);
#pragma unroll
    for (int kk = 0; kk < 8; kk++) {
        short8 a0 = a0p[kk * 4 + quad];
        short8 a1 = a1p[kk * 4 + quad];
        int koff = kk * 32 + quad * 8;
#pragma unroll
        for (int ctl = 0; ctl < 4; ctl++) {
            short8 bfr = *(const short8*)(Bs + (ctl * 16 + mrow) * BROW + koff);
            acc[0][ctl] = __builtin_amdgcn_mfma_f32_16x16x32_bf16(a0, bfr, acc[0][ctl], 0, 0, 0);
            acc[1][ctl] = __builtin_amdgcn_mfma_f32_16x16x32_bf16(a1, bfr, acc[1][ctl], 0, 0, 0);
        }
    }
#pragma unroll
    for (int ctl = 0; ctl < 4; ctl++) {
        int col = cg * 64 + ctl * 16 + mrow;
#pragma unroll
        for (int h = 0; h < 2; h++)
#pragma unroll
            for (int r = 0; r < 4; r++) {
                int node = base + h * 16 + quad * 4 + r;
                float v = acc[h][ctl][r] + bias[ctl];
                H[(size_t)node * 256 + col] = f2bf(fmaxf(v, 0.f));
            }
    }
}

// ---- GEMM2 (col-split, XCD-swizzled): cg 0,1 -> g (fp8); cg 2,3 -> partial f16 (+b2) ----
__global__ __launch_bounds__(256, 4) void k_gemm2(const unsigned short* A, const unsigned short* wb,
                                                  const float* b2, unsigned char* g,
                                                  unsigned short* partial) {
    __shared__ unsigned short Bs[64 * BROW];   // 33 KB
    int t = threadIdx.x;
    int b = blockIdx.x;
    int chunk = (b & 7) + ((b >> 5) << 3);
    int cg = (b >> 3) & 3;
    if (chunk >= NCHUNK) return;
    {
        const short8* src = (const short8*)(wb + (size_t)cg * 64 * 256);
        short8* dst = (short8*)Bs;
#pragma unroll
        for (int i = 0; i < 8; i++) {
            int gi = i * 256 + t;
            int r = gi >> 5, c = gi & 31;
            dst[r * 33 + c] = src[gi];
        }
    }
    __syncthreads();
    int wv = t >> 6, lane = t & 63;
    int mrow = lane & 15, quad = lane >> 4;
    int base = chunk * 128 + wv * 32;
    if (base >= NN) return;
    float bias[4];
#pragma unroll
    for (int ctl = 0; ctl < 4; ctl++)
        bias[ctl] = (cg >= 2) ? b2[cg * 64 + ctl * 16 + mrow - 128] : 0.f;
    float4v acc[2][4];
#pragma unroll
    for (int h = 0; h < 2; h++)
#pragma unroll
        for (int ctl = 0; ctl < 4; ctl++) acc[h][ctl] = (float4v)(0.0f);
    const short8* a0p = (const short8*)(A + (size_t)(base + mrow) * 256);
    const short8* a1p = (const short8*)(A + (size_t)(base + 16 + mrow) * 256);
#pragma unroll
    for (int kk = 0; kk < 8; kk++) {
        short8 a0 = a0p[kk * 4 + quad];
        short8 a1 = a1p[kk * 4 + quad];
        int koff = kk * 32 + quad * 8;
#pragma unroll
        for (int ctl = 0; ctl < 4; ctl++) {
            short8 bfr = *(const short8*)(Bs + (ctl * 16 + mrow) * BROW + koff);
            acc[0][ctl] = __builtin_amdgcn_mfma_f32_16x16x32_bf16(a0, bfr, acc[0][ctl], 0, 0, 0);
            acc[1][ctl] = __builtin_amdgcn_mfma_f32_16x16x32_bf16(a1, bfr, acc[1][ctl], 0, 0, 0);
        }
    }
    if (cg < 2) {
#pragma unroll
        for (int ctl = 0; ctl < 4; ctl++) {
            int col = cg * 64 + ctl * 16 + mrow;   // in [0,128)
#pragma unroll
            for (int h = 0; h < 2; h++)
#pragma unroll
                for (int r = 0; r < 4; r++) {
                    int node = base + h * 16 + quad * 4 + r;
                    g[(size_t)node * 128 + col] = f2fp8(acc[h][ctl][r]);
                }
        }
    } else {
#pragma unroll
        for (int ctl = 0; ctl < 4; ctl++) {
            int pcol = cg * 64 + ctl * 16 + mrow - 128;   // in [0,128)
#pragma unroll
            for (int h = 0; h < 2; h++)
#pragma unroll
                for (int r = 0; r < 4; r++) {
                    int node = base + h * 16 + quad * 4 + r;
                    __half hf = __float2half(acc[h][ctl][r] + bias[ctl]);
                    partial[(size_t)node * 128 + pcol] = __half_as_ushort(hf);
                }
        }
    }
}

extern "C" void kernel_launch(void* const* d_in, const int* in_sizes, int n_in,
                              void* d_out, int out_size, void* d_ws, size_t ws_size,
                              hipStream_t stream) {
    const float* x   = (const float*)d_in[0];
    const int*   ei  = (const int*)d_in[1];
    const float* W1l = (const float*)d_in[2];
    const float* b1  = (const float*)d_in[3];
    const float* W1r = (const float*)d_in[4];
    const float* W2l = (const float*)d_in[5];
    const float* b2  = (const float*)d_in[6];
    const float* W2r = (const float*)d_in[7];
    float* out = (float*)d_out;

    char* p = (char*)d_ws;
    unsigned int* axb = (unsigned int*)p; p += (size_t)NN * 256 * 2;  // [agg(128) | x(128)] bf16
    unsigned short* h = (unsigned short*)p; p += (size_t)NN * 256 * 2;
    unsigned char* g  = (unsigned char*)p; p += (size_t)NN * 128;     // fp8 e4m3
    unsigned short* xf8 = (unsigned short*)p; p += (size_t)NN * 128;  // fp8 e4m3 copy of x
    unsigned short* wb1 = (unsigned short*)p; p += 65536 * 2;
    unsigned short* wb2 = (unsigned short*)p; p += 65536 * 2;
    int* deg  = (int*)p; p += (size_t)NN * 4;
    int* off  = (int*)p; p += (size_t)NN * 4;
    int* csr  = (int*)p; p += (size_t)NE * 4;
    int* bcnt = (int*)p; p += NB * 4;
    int* boff = (int*)p; p += (NB + 1) * 4;
    int* bcur = (int*)p; p += NB * 4;
    if (ws_size < (size_t)(p - (char*)d_ws)) return;
    // optional dense first-16 table (fast agg path) -- only if workspace allows
    int* csr16 = (int*)p; p += (size_t)NN * 16 * 4;
    if (ws_size < (size_t)(p - (char*)d_ws)) csr16 = nullptr;
    unsigned int* pairs = (unsigned int*)h;       // overlay: dead before gemm1 writes h
    unsigned short* partial = (unsigned short*)axb; // overlay: axb dead after gemm1 reads it

    hipMemsetAsync(bcnt, 0, NB * 4, stream);
    k_prep<<<3509, 256, 0, stream>>>(x, W1l, W1r, W2l, W2r, ei, axb, xf8, wb1, wb2, bcnt);
    k_bscan<<<1, NB, 0, stream>>>(bcnt, boff, bcur);
    k_bscatter<<<NCH, 256, 0, stream>>>(ei, bcur, pairs);
    k_build<<<NB, 256, 0, stream>>>(pairs, boff, off, deg, csr, csr16);
    k_agg1<<<12500, 512, 0, stream>>>((const uint2*)xf8, off, deg, csr, csr16, axb);
    k_gemm1<<<GGRID, 256, 0, stream>>>((const unsigned short*)axb, wb1, b1, h);
    k_gemm2<<<GGRID, 256, 0, stream>>>(h, wb2, b2, g, partial);
    k_agg2<<<12500, 512, 0, stream>>>((const uint2*)g, off, deg, csr, csr16, partial, out);
}